// Round 1
// baseline (5338.695 us; speedup 1.0000x reference)
//
#include <hip/hip_runtime.h>

// ---------------------------------------------------------------------------
// 3-layer SimpleRNN, B=256 T=512 U=512 E=128, fp16 MFMA.
// R6: flag-free "tagged dword" exchange. Every exchanged h value is stored as
//   dword = (step_tag << 16) | fp16_bits      (4B stores are atomic)
// so consumers validate data directly: no producer store-ack, no flag publish,
// no separate poll round-trip. Exchange loads are issued speculatively at the
// END of the previous step (overlapped with the epilogue), then validated with
// one vmcnt(0) + tag check + block vote; stale rounds re-issue (~1 RT each).
// Ring-reuse safety keeps one no-ack "consumed" counter per block (3 steps of
// slack, off the critical path). 96 blocks = 3 layers x 8 mgroups x 4 strips,
// 256 thr, register-resident weights, 1 wave/SIMD (VGPR budget 512).
// ---------------------------------------------------------------------------

#define BATCH 256
#define SEQ   512
#define EMBD  128
#define UNIT  512

typedef _Float16 half8 __attribute__((ext_vector_type(8)));
typedef _Float16 half4 __attribute__((ext_vector_type(4)));
typedef float    f32x4 __attribute__((ext_vector_type(4)));
typedef unsigned int uint4v __attribute__((ext_vector_type(4)));
typedef unsigned int uint2v __attribute__((ext_vector_type(2)));

// ws layout (bytes). Ring now holds tagged dwords: slot = 32 rows x 512 dwords.
#define FLAGS_BYTES 4096
#define HBUF_OFF    4096
#define SLOT_BYTES  65536                      // 32*512*4
#define HBUF_BYTES  (3*8*4*SLOT_BYTES)         // 6 MB
#define PWX0_OFF    (HBUF_OFF + HBUF_BYTES)
#define PWH0_OFF    (PWX0_OFF + EMBD*UNIT*2)
#define PWX1_OFF    (PWH0_OFF + UNIT*UNIT*2)
#define PWH1_OFF    (PWX1_OFF + UNIT*UNIT*2)

// ---------------------------------------------------------------------------
__device__ __forceinline__ void sc_st_int(int* p, int v) {
    asm volatile("global_store_dword %0, %1, off sc0 sc1" :: "v"(p), "v"(v) : "memory");
}
__device__ __forceinline__ unsigned hbits(_Float16 h) {
    union { _Float16 f; unsigned short u; } x; x.f = h; return (unsigned)x.u;
}

// ---------------------------------------------------------------------------
__global__ void fill_ws_kernel(uint4v* __restrict__ p, int n16, unsigned pat) {
    int i = blockIdx.x * 256 + threadIdx.x;
    uint4v z = {pat, pat, pat, pat};
    if (i < n16) p[i] = z;
}

// Pack fp32 weight [K][N] into MFMA B-fragment order, fp16 (unchanged):
__global__ void pack_w_kernel(const float* __restrict__ src, _Float16* __restrict__ dst,
                              int K, int N) {
    int idx = blockIdx.x * 256 + threadIdx.x;
    if (idx >= K * N) return;
    int j    = idx & 7;
    int lane = (idx >> 3) & 63;
    int rest = idx >> 9;
    int KT   = K >> 5;
    int kt   = rest % KT;
    int nt   = rest / KT;
    int k = kt*32 + (lane >> 4)*8 + j;
    int n = nt*16 + (lane & 15);
    dst[idx] = (_Float16)src[k * N + n];
}

// ---------------------------------------------------------------------------
// stage one sibling quad (4 tagged dwords = 4 halfs, cols ch0..ch0+3) into Ah
#define STAGE_SIB(Q, CS, II) do {                                              \
    int r_   = (II)*8 + (tid >> 5);                                            \
    int ch0_ = (CS) + (tid & 31)*4;                                            \
    unsigned lo_ = ((Q)[0] & 0xFFFFu) | ((Q)[1] << 16);                        \
    unsigned hi_ = ((Q)[2] & 0xFFFFu) | ((Q)[3] << 16);                        \
    *(uint2v*)((unsigned*)&Ah[r_][0] +                                         \
        ((((ch0_ >> 3) + r_) & 63)*4 + ((ch0_ >> 2) & 1)*2)) = (uint2v){lo_, hi_}; \
} while (0)

#define STAGE_AIN(Q, II) do {                                                  \
    int m_  = (II)*256 + tid;                                                  \
    int r_  = m_ >> 7;                                                         \
    int cg_ = m_ & 127;                                                        \
    unsigned lo_ = ((Q)[0] & 0xFFFFu) | ((Q)[1] << 16);                        \
    unsigned hi_ = ((Q)[2] & 0xFFFFu) | ((Q)[3] << 16);                        \
    *(uint2v*)((unsigned*)&Ain[r_][0] +                                        \
        ((((cg_ >> 1) + r_) & 63)*4 + (cg_ & 1)*2)) = (uint2v){lo_, hi_};      \
} while (0)

// ---------------------------------------------------------------------------
__global__ __launch_bounds__(256, 1)
void rnn_main_kernel(const int*   __restrict__ tokens,
                     const float* __restrict__ emb,
                     const float* __restrict__ b0,
                     const float* __restrict__ b1,
                     char* ws)
{
    const int bid   = blockIdx.x;
    const int layer = bid >> 5;          // 0..2
    const int mg    = (bid >> 2) & 7;    // batch group (32 rows)
    const int ns    = bid & 3;           // N-strip (128 cols)
    const int tid   = threadIdx.x;
    const int wv    = tid >> 6;
    const int lane  = tid & 63;
    const int q     = lane >> 4;
    const int c16   = lane & 15;

    // consumed-progress flags: quad per (layer,mg), written by that layer's
    // 4 strip-blocks after their input loads retire; read by the layer above.
    int* flags  = (int*)ws;
    int* qDn    = flags + ((layer < 2 ? layer + 1 : layer)*8 + mg)*32;
    int* myCons = flags + (layer*8 + mg)*32 + ns;

    char* hbuf = ws + HBUF_OFF;
    const _Float16* pWh = (const _Float16*)(ws + (layer == 0 ? PWH0_OFF : PWH1_OFF));
    const _Float16* pWx = (const _Float16*)(ws + (layer == 0 ? PWX0_OFF : PWX1_OFF));
    const float* bias = (layer == 0) ? b0 : b1;

    const int c0  = ns*128 + wv*32;      // global col base of this wave
    const int nt0 = c0 >> 4;
    const int m0  = mg * 32;
    const int bc0 = ns * 128;            // block strip col base

    const int sA = (ns == 0) ? 1 : 0;
    const int sB = (ns <= 1) ? 2 : 1;
    const int sC = (ns <= 2) ? 3 : 2;
    const int CsA = sA*128, CsB = sB*128, CsC = sC*128;

    __shared__ __align__(16) _Float16 Ah [32][512];
    __shared__ __align__(16) _Float16 Ain[32][512];
    __shared__ __align__(16) unsigned Bounce[32][128];   // tagged dwords
    __shared__ int wflag[4];

    // zero Ah: h(-1) = 0 (own strip; sibling cols staged from prefilled ring)
    {
        uint4v z = {0u,0u,0u,0u};
#pragma unroll
        for (int i = 0; i < 8; ++i) ((uint4v*)Ah)[i*256 + tid] = z;
    }

    // ---- register-resident weights (B-fragments) ----
    half8 whf[16][2];
    half8 wxf[16][2];
#pragma unroll
    for (int kt = 0; kt < 16; ++kt)
#pragma unroll
        for (int n = 0; n < 2; ++n)
            whf[kt][n] = *(const half8*)&pWh[(((nt0 + n)*16 + kt)*64 + lane) * 8];
    if (layer == 0) {
#pragma unroll
        for (int kt = 0; kt < 4; ++kt)
#pragma unroll
            for (int n = 0; n < 2; ++n)
                wxf[kt][n] = *(const half8*)&pWx[(((nt0 + n)*4 + kt)*64 + lane) * 8];
    } else {
#pragma unroll
        for (int kt = 0; kt < 16; ++kt)
#pragma unroll
            for (int n = 0; n < 2; ++n)
                wxf[kt][n] = *(const half8*)&pWx[(((nt0 + n)*16 + kt)*64 + lane) * 8];
    }

    const float bv0 = bias[c0 + c16];
    const float bv1 = bias[c0 + 16 + c16];

    // per-thread voffsets for the exchange clauses
    const unsigned voff_sib = ((unsigned)(tid >> 5))*2048u + ((unsigned)(tid & 31))*16u;
    const unsigned vsf0 = voff_sib, vsf1 = voff_sib + 16384u,
                   vsf2 = voff_sib + 32768u, vsf3 = voff_sib + 49152u;
    const unsigned vaf0 = (unsigned)tid*16u, vaf1 = vaf0 + 4096u,
                   vaf2 = vaf0 + 8192u, vaf3 = vaf0 + 12288u;
    const unsigned voff_st = ((unsigned)(tid >> 3))*2048u + ((unsigned)(tid & 7))*64u;

    // exchange clause registers (held live across the step boundary)
    uint4v s0,s1,s2,s3,s4,s5,s6,s7,s8,s9,s10,s11;          // sibling quads
    uint4v a0,a1,a2,a3,a4,a5,a6,a7,a8,a9,a10,a11,a12,a13,a14,a15; // Ain quads
    uint4v fq;                                              // consumed quad
    uint4v sv0 = {0,0,0,0}, sv1 = {0,0,0,0}, sv2 = {0,0,0,0}, sv3 = {0,0,0,0};

    // issue the full exchange clause for step tt (no wait inside)
    auto issue_all = [&](int tt) {
        {
            const char* sb = hbuf + (size_t)((layer*8 + mg)*4 + ((tt + 3) & 3)) * SLOT_BYTES;
            const char* bA = sb + CsA*4;
            const char* bB = sb + CsB*4;
            const char* bC = sb + CsC*4;
            asm volatile(
                "global_load_dwordx4 %0,  %12, %16 sc0 sc1\n\t"
                "global_load_dwordx4 %1,  %13, %16 sc0 sc1\n\t"
                "global_load_dwordx4 %2,  %14, %16 sc0 sc1\n\t"
                "global_load_dwordx4 %3,  %15, %16 sc0 sc1\n\t"
                "global_load_dwordx4 %4,  %12, %17 sc0 sc1\n\t"
                "global_load_dwordx4 %5,  %13, %17 sc0 sc1\n\t"
                "global_load_dwordx4 %6,  %14, %17 sc0 sc1\n\t"
                "global_load_dwordx4 %7,  %15, %17 sc0 sc1\n\t"
                "global_load_dwordx4 %8,  %12, %18 sc0 sc1\n\t"
                "global_load_dwordx4 %9,  %13, %18 sc0 sc1\n\t"
                "global_load_dwordx4 %10, %14, %18 sc0 sc1\n\t"
                "global_load_dwordx4 %11, %15, %18 sc0 sc1"
                : "=&v"(s0),"=&v"(s1),"=&v"(s2),"=&v"(s3),"=&v"(s4),"=&v"(s5),
                  "=&v"(s6),"=&v"(s7),"=&v"(s8),"=&v"(s9),"=&v"(s10),"=&v"(s11)
                : "v"(vsf0),"v"(vsf1),"v"(vsf2),"v"(vsf3),"s"(bA),"s"(bB),"s"(bC)
                : "memory");
            asm volatile("global_load_dwordx4 %0, %1, off sc0 sc1"
                : "=&v"(fq) : "v"(qDn) : "memory");
        }
        if (layer > 0) {
            const char* ab = hbuf + (size_t)(((layer - 1)*8 + mg)*4 + (tt & 3)) * SLOT_BYTES;
            asm volatile(
                "global_load_dwordx4 %0, %8,  %12 sc0 sc1\n\t"
                "global_load_dwordx4 %1, %9,  %12 sc0 sc1\n\t"
                "global_load_dwordx4 %2, %10, %12 sc0 sc1\n\t"
                "global_load_dwordx4 %3, %11, %12 sc0 sc1\n\t"
                "global_load_dwordx4 %4, %8,  %13 sc0 sc1\n\t"
                "global_load_dwordx4 %5, %9,  %13 sc0 sc1\n\t"
                "global_load_dwordx4 %6, %10, %13 sc0 sc1\n\t"
                "global_load_dwordx4 %7, %11, %13 sc0 sc1"
                : "=&v"(a0),"=&v"(a1),"=&v"(a2),"=&v"(a3),
                  "=&v"(a4),"=&v"(a5),"=&v"(a6),"=&v"(a7)
                : "v"(vaf0),"v"(vaf1),"v"(vaf2),"v"(vaf3),"s"(ab),"s"(ab + 16384)
                : "memory");
            asm volatile(
                "global_load_dwordx4 %0, %8,  %12 sc0 sc1\n\t"
                "global_load_dwordx4 %1, %9,  %12 sc0 sc1\n\t"
                "global_load_dwordx4 %2, %10, %12 sc0 sc1\n\t"
                "global_load_dwordx4 %3, %11, %12 sc0 sc1\n\t"
                "global_load_dwordx4 %4, %8,  %13 sc0 sc1\n\t"
                "global_load_dwordx4 %5, %9,  %13 sc0 sc1\n\t"
                "global_load_dwordx4 %6, %10, %13 sc0 sc1\n\t"
                "global_load_dwordx4 %7, %11, %13 sc0 sc1"
                : "=&v"(a8),"=&v"(a9),"=&v"(a10),"=&v"(a11),
                  "=&v"(a12),"=&v"(a13),"=&v"(a14),"=&v"(a15)
                : "v"(vaf0),"v"(vaf1),"v"(vaf2),"v"(vaf3),"s"(ab + 32768),"s"(ab + 49152)
                : "memory");
        }
    };

    issue_all(0);

    for (int t = 0; t < SEQ; ++t) {
        const unsigned exps = ((unsigned)((t - 1) & 0xFFFF)) << 16;  // sibling tag
        const unsigned expa = ((unsigned)( t      & 0xFFFF)) << 16;  // up-layer tag
        const uint4v exps4 = {exps, exps, exps, exps};
        const uint4v expa4 = {expa, expa, expa, expa};

        // ---- validate exchange data (retry-reload on staleness) ----
        for (;;) {
            asm volatile("s_waitcnt vmcnt(0)"
                : "+v"(s0),"+v"(s1),"+v"(s2),"+v"(s3),"+v"(s4),"+v"(s5),
                  "+v"(s6),"+v"(s7),"+v"(s8),"+v"(s9),"+v"(s10),"+v"(s11)
                : "v"(sv0),"v"(sv1),"v"(sv2),"v"(sv3)
                : "memory");
            if (layer > 0) {
                asm volatile("" : "+v"(a0),"+v"(a1),"+v"(a2),"+v"(a3),
                                  "+v"(a4),"+v"(a5),"+v"(a6),"+v"(a7) :: "memory");
                asm volatile("" : "+v"(a8),"+v"(a9),"+v"(a10),"+v"(a11),
                                  "+v"(a12),"+v"(a13),"+v"(a14),"+v"(a15),"+v"(fq) :: "memory");
            } else {
                asm volatile("" : "+v"(fq) :: "memory");
            }

            uint4v badv = {0u,0u,0u,0u};
            badv |= (s0 ^ exps4);  badv |= (s1 ^ exps4);  badv |= (s2  ^ exps4);
            badv |= (s3 ^ exps4);  badv |= (s4 ^ exps4);  badv |= (s5  ^ exps4);
            badv |= (s6 ^ exps4);  badv |= (s7 ^ exps4);  badv |= (s8  ^ exps4);
            badv |= (s9 ^ exps4);  badv |= (s10 ^ exps4); badv |= (s11 ^ exps4);
            if (layer > 0) {
                badv |= (a0  ^ expa4); badv |= (a1  ^ expa4); badv |= (a2  ^ expa4);
                badv |= (a3  ^ expa4); badv |= (a4  ^ expa4); badv |= (a5  ^ expa4);
                badv |= (a6  ^ expa4); badv |= (a7  ^ expa4); badv |= (a8  ^ expa4);
                badv |= (a9  ^ expa4); badv |= (a10 ^ expa4); badv |= (a11 ^ expa4);
                badv |= (a12 ^ expa4); badv |= (a13 ^ expa4); badv |= (a14 ^ expa4);
                badv |= (a15 ^ expa4);
            }
            unsigned bad = (badv[0] | badv[1] | badv[2] | badv[3]) & 0xFFFF0000u;
            if (layer < 2) {   // ring-reuse: down layer secured step t-4 of our slot
                int mn = (int)fq[0];
                mn = ((int)fq[1] < mn) ? (int)fq[1] : mn;
                mn = ((int)fq[2] < mn) ? (int)fq[2] : mn;
                mn = ((int)fq[3] < mn) ? (int)fq[3] : mn;
                if (mn < t - 3) bad |= 1u;
            }
            unsigned long long wb = __ballot(bad != 0u);
            if (lane == 0) wflag[wv] = (wb != 0ull) ? 1 : 0;
            __syncthreads();
            int any = wflag[0] | wflag[1] | wflag[2] | wflag[3];
            __syncthreads();
            if (!any) break;
            issue_all(t);
        }

        // our input loads have retired -> up layer may reuse its ring slot
        if (layer > 0 && tid == 0) sc_st_int(myCons, t + 1);

        // ---- stage siblings -> Ah ----
        STAGE_SIB(s0, CsA, 0); STAGE_SIB(s1, CsA, 1); STAGE_SIB(s2,  CsA, 2); STAGE_SIB(s3,  CsA, 3);
        STAGE_SIB(s4, CsB, 0); STAGE_SIB(s5, CsB, 1); STAGE_SIB(s6,  CsB, 2); STAGE_SIB(s7,  CsB, 3);
        STAGE_SIB(s8, CsC, 0); STAGE_SIB(s9, CsC, 1); STAGE_SIB(s10, CsC, 2); STAGE_SIB(s11, CsC, 3);

        if (layer > 0) {
            STAGE_AIN(a0, 0);  STAGE_AIN(a1, 1);  STAGE_AIN(a2, 2);  STAGE_AIN(a3, 3);
            STAGE_AIN(a4, 4);  STAGE_AIN(a5, 5);  STAGE_AIN(a6, 6);  STAGE_AIN(a7, 7);
            STAGE_AIN(a8, 8);  STAGE_AIN(a9, 9);  STAGE_AIN(a10,10); STAGE_AIN(a11,11);
            STAGE_AIN(a12,12); STAGE_AIN(a13,13); STAGE_AIN(a14,14); STAGE_AIN(a15,15);
        } else {
            // layer 0: embedding gather (plain cached loads)
#pragma unroll
            for (int i = 0; i < 4; ++i) {
                int idx = i*256 + tid;
                int r   = idx >> 5;
                int qq  = idx & 31;
                int tok = tokens[(m0 + r)*SEQ + t];
                float4 f = *((const float4*)(emb + (long)tok * EMBD) + qq);
                half4 h = { (_Float16)f.x, (_Float16)f.y, (_Float16)f.z, (_Float16)f.w };
                *(half4*)&Ain[r][((((qq >> 1) + r) & 63) * 8) + (qq & 1) * 4] = h;
            }
        }
        __syncthreads();   // (C1) Ah + Ain ready

        f32x4 acc00 = {0,0,0,0}, acc01 = {0,0,0,0}, acc10 = {0,0,0,0}, acc11 = {0,0,0,0};

        if (layer > 0) {
#pragma unroll
            for (int kt = 0; kt < 16; ++kt) {
                half8 fa0 = *(const half8*)&Ah[c16]     [((kt*4 + q + c16)      & 63) * 8];
                half8 fa1 = *(const half8*)&Ah[16 + c16][((kt*4 + q + 16 + c16) & 63) * 8];
                acc00 = __builtin_amdgcn_mfma_f32_16x16x32_f16(fa0, whf[kt][0], acc00, 0, 0, 0);
                acc01 = __builtin_amdgcn_mfma_f32_16x16x32_f16(fa0, whf[kt][1], acc01, 0, 0, 0);
                acc10 = __builtin_amdgcn_mfma_f32_16x16x32_f16(fa1, whf[kt][0], acc10, 0, 0, 0);
                acc11 = __builtin_amdgcn_mfma_f32_16x16x32_f16(fa1, whf[kt][1], acc11, 0, 0, 0);
            }
#pragma unroll
            for (int kt = 0; kt < 16; ++kt) {
                half8 fa0 = *(const half8*)&Ain[c16]     [((kt*4 + q + c16)      & 63) * 8];
                half8 fa1 = *(const half8*)&Ain[16 + c16][((kt*4 + q + 16 + c16) & 63) * 8];
                acc00 = __builtin_amdgcn_mfma_f32_16x16x32_f16(fa0, wxf[kt][0], acc00, 0, 0, 0);
                acc01 = __builtin_amdgcn_mfma_f32_16x16x32_f16(fa0, wxf[kt][1], acc01, 0, 0, 0);
                acc10 = __builtin_amdgcn_mfma_f32_16x16x32_f16(fa1, wxf[kt][0], acc10, 0, 0, 0);
                acc11 = __builtin_amdgcn_mfma_f32_16x16x32_f16(fa1, wxf[kt][1], acc11, 0, 0, 0);
            }
        } else {
#pragma unroll
            for (int kt = 0; kt < 16; ++kt) {
                half8 fa0 = *(const half8*)&Ah[c16]     [((kt*4 + q + c16)      & 63) * 8];
                half8 fa1 = *(const half8*)&Ah[16 + c16][((kt*4 + q + 16 + c16) & 63) * 8];
                acc00 = __builtin_amdgcn_mfma_f32_16x16x32_f16(fa0, whf[kt][0], acc00, 0, 0, 0);
                acc01 = __builtin_amdgcn_mfma_f32_16x16x32_f16(fa0, whf[kt][1], acc01, 0, 0, 0);
                acc10 = __builtin_amdgcn_mfma_f32_16x16x32_f16(fa1, whf[kt][0], acc10, 0, 0, 0);
                acc11 = __builtin_amdgcn_mfma_f32_16x16x32_f16(fa1, whf[kt][1], acc11, 0, 0, 0);
            }
#pragma unroll
            for (int kt = 0; kt < 4; ++kt) {
                half8 fa0 = *(const half8*)&Ain[c16]     [((kt*4 + q + c16)      & 63) * 8];
                half8 fa1 = *(const half8*)&Ain[16 + c16][((kt*4 + q + 16 + c16) & 63) * 8];
                acc00 = __builtin_amdgcn_mfma_f32_16x16x32_f16(fa0, wxf[kt][0], acc00, 0, 0, 0);
                acc01 = __builtin_amdgcn_mfma_f32_16x16x32_f16(fa0, wxf[kt][1], acc01, 0, 0, 0);
                acc10 = __builtin_amdgcn_mfma_f32_16x16x32_f16(fa1, wxf[kt][0], acc10, 0, 0, 0);
                acc11 = __builtin_amdgcn_mfma_f32_16x16x32_f16(fa1, wxf[kt][1], acc11, 0, 0, 0);
            }
        }

        // ---- tanh -> hv regs + tagged Bounce ----
        const unsigned tagw = ((unsigned)t) << 16;
        _Float16 hv[16];
#pragma unroll
        for (int r = 0; r < 4; ++r) {
            int row0 = q*4 + r, row1 = 16 + row0;
            float z, e; _Float16 v;
            z = acc00[r] + bv0; e = __expf(2.0f*z); v = (_Float16)(1.0f - 2.0f/(e + 1.0f));
            hv[r*4+0] = v; Bounce[row0][wv*32 + c16]      = tagw | hbits(v);
            z = acc01[r] + bv1; e = __expf(2.0f*z); v = (_Float16)(1.0f - 2.0f/(e + 1.0f));
            hv[r*4+1] = v; Bounce[row0][wv*32 + 16 + c16] = tagw | hbits(v);
            z = acc10[r] + bv0; e = __expf(2.0f*z); v = (_Float16)(1.0f - 2.0f/(e + 1.0f));
            hv[r*4+2] = v; Bounce[row1][wv*32 + c16]      = tagw | hbits(v);
            z = acc11[r] + bv1; e = __expf(2.0f*z); v = (_Float16)(1.0f - 2.0f/(e + 1.0f));
            hv[r*4+3] = v; Bounce[row1][wv*32 + 16 + c16] = tagw | hbits(v);
        }
        __syncthreads();   // (D) all MFMA reads of Ah/Ain done; Bounce complete

        // ---- own strip -> Ah(t) ----
        {
            int g0 = c0 + c16, g1 = c0 + 16 + c16;
#pragma unroll
            for (int r = 0; r < 4; ++r) {
                int row0 = q*4 + r, row1 = 16 + row0;
                Ah[row0][(((g0 >> 3) + row0) & 63)*8 + (g0 & 7)] = hv[r*4+0];
                Ah[row0][(((g1 >> 3) + row0) & 63)*8 + (g1 & 7)] = hv[r*4+1];
                Ah[row1][(((g0 >> 3) + row1) & 63)*8 + (g0 & 7)] = hv[r*4+2];
                Ah[row1][(((g1 >> 3) + row1) & 63)*8 + (g1 & 7)] = hv[r*4+3];
            }
        }

        // ---- Bounce -> ring (coalesced, NO drain: sources pinned via next wait) ----
        {
            const uint4v* bp = (const uint4v*)&Bounce[0][0];
            sv0 = bp[4*tid + 0]; sv1 = bp[4*tid + 1];
            sv2 = bp[4*tid + 2]; sv3 = bp[4*tid + 3];
            const char* stb = hbuf + (size_t)((layer*8 + mg)*4 + (t & 3)) * SLOT_BYTES + bc0*4;
            asm volatile(
                "global_store_dwordx4 %4, %0, %5 sc0 sc1\n\t"
                "global_store_dwordx4 %4, %1, %5 offset:16 sc0 sc1\n\t"
                "global_store_dwordx4 %4, %2, %5 offset:32 sc0 sc1\n\t"
                "global_store_dwordx4 %4, %3, %5 offset:48 sc0 sc1"
                :: "v"(sv0),"v"(sv1),"v"(sv2),"v"(sv3),"v"(voff_st),"s"(stb)
                : "memory");
        }

        // speculatively issue next step's exchange clause (overlaps store flight)
        if (t + 1 < SEQ) issue_all(t + 1);
    }

    // drain final ring stores before endpgm
    asm volatile("s_waitcnt vmcnt(0)" :: "v"(sv0),"v"(sv1),"v"(sv2),"v"(sv3) : "memory");
}

// ---------------------------------------------------------------------------
// logits = h2(T-1) @ fc_w + fc_b ; out = sigmoid(logits). One wave per row.
// h2 stored as tagged dwords (payload in lo16).
__global__ void fc_kernel(const char* __restrict__ ws,
                          const float* __restrict__ fc_w,
                          const float* __restrict__ fc_b,
                          float* __restrict__ out)
{
    int row  = blockIdx.x;
    int lane = threadIdx.x;          // 64
    int m = row >> 5, lr = row & 31;
    const unsigned* h2 = (const unsigned*)(ws + HBUF_OFF
                         + (size_t)(((2*8 + m)*4 + 3)) * SLOT_BYTES)   // slot 511&3 = 3
                         + lr * UNIT;
    float s = 0.0f;
#pragma unroll
    for (int j = 0; j < 8; ++j) {
        unsigned d = h2[lane*8 + j];
        union { unsigned short u; _Float16 f; } x; x.u = (unsigned short)(d & 0xFFFFu);
        s += (float)x.f * fc_w[lane*8 + j];
    }
#pragma unroll
    for (int off = 32; off > 0; off >>= 1) s += __shfl_down(s, off);
    if (lane == 0) {
        float logit = s + fc_b[0];
        out[row] = 1.0f / (1.0f + __expf(-logit));
    }
}

// ---------------------------------------------------------------------------
extern "C" void kernel_launch(void* const* d_in, const int* in_sizes, int n_in,
                              void* d_out, int out_size, void* d_ws, size_t ws_size,
                              hipStream_t stream)
{
    const int*   tokens = (const int*)  d_in[0];
    const float* emb    = (const float*)d_in[1];
    const float* Wx0    = (const float*)d_in[2];
    const float* Wh0    = (const float*)d_in[3];
    const float* b0     = (const float*)d_in[4];
    const float* Wx1    = (const float*)d_in[5];
    const float* Wh1    = (const float*)d_in[6];
    const float* b1     = (const float*)d_in[7];
    const float* fcw    = (const float*)d_in[8];
    const float* fcb    = (const float*)d_in[9];
    char*  ws  = (char*)d_ws;
    float* out = (float*)d_out;

    // 1) flags = 0; ring prefilled with {tag=0xFFFF, payload=0} so t=0's
    //    sibling reads (expected tag (0-1)&0xFFFF) see valid h(-1)=0.
    int n16f = FLAGS_BYTES / 16;
    fill_ws_kernel<<<(n16f + 255)/256, 256, 0, stream>>>((uint4v*)ws, n16f, 0u);
    int n16r = HBUF_BYTES / 16;
    fill_ws_kernel<<<(n16r + 255)/256, 256, 0, stream>>>((uint4v*)(ws + HBUF_OFF), n16r, 0xFFFF0000u);

    // 2) pack weights fp32 -> fp16 B-fragment layout
    pack_w_kernel<<<(EMBD*UNIT + 255)/256, 256, 0, stream>>>(Wx0, (_Float16*)(ws + PWX0_OFF), EMBD, UNIT);
    pack_w_kernel<<<(UNIT*UNIT + 255)/256, 256, 0, stream>>>(Wh0, (_Float16*)(ws + PWH0_OFF), UNIT, UNIT);
    pack_w_kernel<<<(UNIT*UNIT + 255)/256, 256, 0, stream>>>(Wx1, (_Float16*)(ws + PWX1_OFF), UNIT, UNIT);
    pack_w_kernel<<<(UNIT*UNIT + 255)/256, 256, 0, stream>>>(Wh1, (_Float16*)(ws + PWH1_OFF), UNIT, UNIT);

    // 3) pipelined recurrence
    rnn_main_kernel<<<96, 256, 0, stream>>>(tokens, emb, b0, b1, ws);

    // 4) final FC + sigmoid
    fc_kernel<<<256, 64, 0, stream>>>((const char*)ws, fcw, fcb, out);
}